// Round 4
// baseline (689.633 us; speedup 1.0000x reference)
//
#include <hip/hip_runtime.h>
#include <hip/hip_bf16.h>

// ---------------------------------------------------------------------------
// GCN 2-layer forward on MI355X (gfx950).
//   prep: multipass degree histogram -> dinv -> prefix-scan
//   fused: [scatter blocks | gemm1 blocks] in ONE launch (independent work;
//          scatter is latency/write-bound, gemm1 is MFMA-bound -> co-schedule)
//   scatter: chunk-per-block (L1-resident), 16 dst-range passes so all
//          concurrent CSR writes land in one ~800KB L2-resident window
//          (R3: 8x write amplification, 101MB HBM writes for 12.8MB payload)
//   agg: 1 wave/node, half-wave per row (uint2/lane), 2 edges/instr,
//          unroll 4 -> 8 edges in flight, __shfl_xor(32) reduce, fp32 accum
//   L1: gemm_mfma<A=f32>(x,Wt1)->h_bf16 ; agg<out=bf16> -> a1_bf16
//   L2: gemm_mfma<A=bf16>(a1,Wt2)->h_bf16 ; agg<out=f32> -> d_out
// ---------------------------------------------------------------------------

#define DIN 256
#define DH 128
#define NPASS 16

typedef __attribute__((ext_vector_type(8))) short short8;
typedef __attribute__((ext_vector_type(4))) float f32x4;

__device__ __forceinline__ unsigned short f2bf(float f) {
    union { float f; unsigned int i; } c;
    c.f = f;
    unsigned int r = c.i + 0x7FFFu + ((c.i >> 16) & 1u);  // RNE
    return (unsigned short)(r >> 16);
}
__device__ __forceinline__ float bf_lo(unsigned int u) {
    union { unsigned int i; float f; } c;
    c.i = u << 16;
    return c.f;
}
__device__ __forceinline__ float bf_hi(unsigned int u) {
    union { unsigned int i; float f; } c;
    c.i = u & 0xFFFF0000u;
    return c.f;
}

// ---------------- prep ----------------
// chunk-per-block + 16 dst-range passes: chunk stays in L1, atomics localized.
__global__ __launch_bounds__(256) void count_mp(const int* __restrict__ dst,
                                                int* __restrict__ cnt, int e, int n) {
    int nb = gridDim.x;
    int chunk = (e + nb - 1) / nb;
    int beg = blockIdx.x * chunk, end = min(e, beg + chunk);
    int per = (n + NPASS - 1) / NPASS;
    for (int p = 0; p < NPASS; ++p) {
        int lo = p * per, hi = min(n, lo + per);
        for (int i = beg + (int)threadIdx.x; i < end; i += 256) {
            int d = dst[i];
            if (d >= lo && d < hi) atomicAdd(&cnt[d], 1);
        }
    }
}

__global__ void dinv_k(const int* __restrict__ cnt, float* __restrict__ dinv, int n) {
    int i = blockIdx.x * 256 + threadIdx.x;
    if (i < n) dinv[i] = 1.0f / sqrtf((float)(cnt[i] + 1));
}

__global__ void block_sum_k(const int* __restrict__ cnt, int* __restrict__ bsum, int n) {
    __shared__ int s[256];
    int t = threadIdx.x;
    int i = blockIdx.x * 256 + t;
    s[t] = (i < n) ? cnt[i] : 0;
    __syncthreads();
    for (int off = 128; off > 0; off >>= 1) {
        if (t < off) s[t] += s[t + off];
        __syncthreads();
    }
    if (t == 0) bsum[blockIdx.x] = s[0];
}

__global__ void scan_bsum_k(int* __restrict__ bsum, int nb) {
    __shared__ int s[512];
    int t = threadIdx.x;
    s[t] = (t < nb) ? bsum[t] : 0;
    __syncthreads();
    for (int off = 1; off < 512; off <<= 1) {
        int x = (t >= off) ? s[t - off] : 0;
        __syncthreads();
        s[t] += x;
        __syncthreads();
    }
    if (t < nb) bsum[t] = (t == 0) ? 0 : s[t - 1];
}

__global__ void scan_write_k(const int* __restrict__ cnt, const int* __restrict__ bsum,
                             int* __restrict__ rowptr, int* __restrict__ cursor, int n) {
    __shared__ int s[256];
    int t = threadIdx.x;
    int i = blockIdx.x * 256 + t;
    int c = (i < n) ? cnt[i] : 0;
    s[t] = c;
    __syncthreads();
    for (int off = 1; off < 256; off <<= 1) {
        int x = (t >= off) ? s[t - off] : 0;
        __syncthreads();
        s[t] += x;
        __syncthreads();
    }
    int excl = s[t] - c + bsum[blockIdx.x];
    if (i < n) {
        rowptr[i] = excl;
        cursor[i] = excl;
        if (i == n - 1) rowptr[n] = excl + c;
    }
}

// W [K][128] f32 -> Wt [128][K] bf16
__global__ void wt_k(const float* __restrict__ W, unsigned short* __restrict__ Wt, int K) {
    int i = blockIdx.x * 256 + threadIdx.x;
    if (i < K * 128) {
        int k = i >> 7, n = i & 127;
        Wt[(size_t)n * K + k] = f2bf(W[i]);
    }
}

// ---------------- scatter body (multipass, chunk-per-block) ----------------
__device__ __forceinline__ void scatter_body(int bx, int nb, const int* __restrict__ src,
                                             const int* __restrict__ dst,
                                             const float* __restrict__ dinv,
                                             int* __restrict__ cursor,
                                             int2* __restrict__ einfo, int e, int n) {
    int chunk = (e + nb - 1) / nb;
    int beg = bx * chunk, end = min(e, beg + chunk);
    int per = (n + NPASS - 1) / NPASS;
    for (int p = 0; p < NPASS; ++p) {
        int lo = p * per, hi = min(n, lo + per);
        for (int i = beg + (int)threadIdx.x; i < end; i += 256) {
            int d = dst[i];
            if (d >= lo && d < hi) {
                int s = src[i];
                int pos = atomicAdd(&cursor[d], 1);
                einfo[pos] = make_int2(s, __float_as_int(dinv[s] * dinv[d]));
            }
        }
    }
}

// ---------------- GEMM body (MFMA bf16) ----------------
// C[M,128] = A[M,K] @ Wt^T ; Wt is [128][K] bf16. Output Hb [M][128] bf16.
template <bool A_BF16>
__device__ __forceinline__ void gemm_body(int bx, const void* __restrict__ Av,
                                          const unsigned short* __restrict__ Wt,
                                          unsigned short* __restrict__ Hb, int M, int K,
                                          unsigned short* Bt) {
    const int t = threadIdx.x;
    const int w = t >> 6;
    const int lane = t & 63;
    const int l15 = lane & 15;
    const int quad = lane >> 4;
    const int row0 = bx * 128 + w * 32;

    const float* Af = (const float*)Av;
    const unsigned short* Ab = (const unsigned short*)Av;

    f32x4 acc[2][8];
#pragma unroll
    for (int rt = 0; rt < 2; ++rt)
#pragma unroll
        for (int ct = 0; ct < 8; ++ct)
#pragma unroll
            for (int j = 0; j < 4; ++j) acc[rt][ct][j] = 0.0f;

    for (int kc = 0; kc < K; kc += 128) {
        if (kc) __syncthreads();
        // stage B chunk, fragment-major: group fg=(ks*8+ct), lane-contiguous 16B
#pragma unroll
        for (int i = 0; i < 8; ++i) {
            int fg = w * 8 + i;
            int ks = fg >> 3, ct = fg & 7;
            int nn = ct * 16 + l15;
            int gk = ks * 32 + quad * 8;
            *(short8*)&Bt[fg * 512 + lane * 8] =
                *(const short8*)(Wt + (size_t)nn * K + kc + gk);
        }
        __syncthreads();
#pragma unroll
        for (int ks = 0; ks < 4; ++ks) {
            int kk = ks * 32 + quad * 8;
            short8 af[2];
#pragma unroll
            for (int rt = 0; rt < 2; ++rt) {
                int row = row0 + rt * 16 + l15;
                if (row < M) {
                    if (A_BF16) {
                        af[rt] = *(const short8*)(Ab + (size_t)row * K + kc + kk);
                    } else {
                        const float* p = Af + (size_t)row * K + kc + kk;
                        float4 x0 = *(const float4*)p;
                        float4 x1 = *(const float4*)(p + 4);
                        af[rt][0] = (short)f2bf(x0.x);
                        af[rt][1] = (short)f2bf(x0.y);
                        af[rt][2] = (short)f2bf(x0.z);
                        af[rt][3] = (short)f2bf(x0.w);
                        af[rt][4] = (short)f2bf(x1.x);
                        af[rt][5] = (short)f2bf(x1.y);
                        af[rt][6] = (short)f2bf(x1.z);
                        af[rt][7] = (short)f2bf(x1.w);
                    }
                } else {
#pragma unroll
                    for (int j = 0; j < 8; ++j) af[rt][j] = 0;
                }
            }
#pragma unroll
            for (int ct = 0; ct < 8; ++ct) {
                short8 bfr = *(const short8*)&Bt[(ks * 8 + ct) * 512 + lane * 8];
                acc[0][ct] = __builtin_amdgcn_mfma_f32_16x16x32_bf16(af[0], bfr, acc[0][ct], 0, 0, 0);
                acc[1][ct] = __builtin_amdgcn_mfma_f32_16x16x32_bf16(af[1], bfr, acc[1][ct], 0, 0, 0);
            }
        }
    }
#pragma unroll
    for (int rt = 0; rt < 2; ++rt)
#pragma unroll
        for (int r = 0; r < 4; ++r) {
            int row = row0 + rt * 16 + quad * 4 + r;
            if (row < M) {
                unsigned short* o = Hb + (size_t)row * 128 + l15;
#pragma unroll
                for (int ct = 0; ct < 8; ++ct) o[ct * 16] = f2bf(acc[rt][ct][r]);
            }
        }
}

template <bool A_BF16>
__global__ __launch_bounds__(256) void gemm_mfma(const void* __restrict__ Av,
                                                 const unsigned short* __restrict__ Wt,
                                                 unsigned short* __restrict__ Hb,
                                                 int M, int K) {
    __shared__ unsigned short Bt[16384];
    gemm_body<A_BF16>(blockIdx.x, Av, Wt, Hb, M, K, Bt);
}

// fused: blocks [0,SB) scatter, blocks [SB, SB+GB) gemm layer 1
__global__ __launch_bounds__(256) void gemm1_scatter_k(
    const float* __restrict__ x, const unsigned short* __restrict__ Wt1,
    unsigned short* __restrict__ Hb, int M,
    const int* __restrict__ src, const int* __restrict__ dst,
    const float* __restrict__ dinv, int* __restrict__ cursor,
    int2* __restrict__ einfo, int e, int n, int SB) {
    __shared__ unsigned short Bt[16384];
    if ((int)blockIdx.x < SB)
        scatter_body(blockIdx.x, SB, src, dst, dinv, cursor, einfo, e, n);
    else
        gemm_body<false>(blockIdx.x - SB, x, Wt1, Hb, M, DIN, Bt);
}

// ---------------- aggregation ----------------
// 1 wave/node; half-wave (32 lanes) covers a 256B bf16 row via uint2/lane.
// halves process even/odd edges; unroll 4 -> 8 edges in flight.
template <bool OUT_BF16>
__global__ __launch_bounds__(256) void agg_k(const unsigned short* __restrict__ Hb,
                                             const int* __restrict__ rowptr,
                                             const int2* __restrict__ einfo,
                                             const float* __restrict__ dinv,
                                             const float* __restrict__ bias,
                                             void* __restrict__ out, int n) {
    int v = blockIdx.x * 4 + (threadIdx.x >> 6);
    int lane = threadIdx.x & 63;
    if (v >= n) return;
    int l = lane & 31, half = lane >> 5;
    const uint2* __restrict__ H = (const uint2*)Hb;  // row = 32 x uint2
    float a0 = 0.f, a1 = 0.f, a2 = 0.f, a3 = 0.f;
    if (half == 0) {
        float dv = dinv[v];
        float self = dv * dv;
        uint2 hv = H[(size_t)v * 32 + l];
        a0 = self * bf_lo(hv.x); a1 = self * bf_hi(hv.x);
        a2 = self * bf_lo(hv.y); a3 = self * bf_hi(hv.y);
    }
    int end = rowptr[v + 1];
    int i = rowptr[v] + half;
    for (; i + 6 < end; i += 8) {
        int2 e0 = einfo[i], e1 = einfo[i + 2], e2 = einfo[i + 4], e3 = einfo[i + 6];
        uint2 v0 = H[(size_t)e0.x * 32 + l];
        uint2 v1 = H[(size_t)e1.x * 32 + l];
        uint2 v2 = H[(size_t)e2.x * 32 + l];
        uint2 v3 = H[(size_t)e3.x * 32 + l];
        float w0 = __int_as_float(e0.y), w1 = __int_as_float(e1.y);
        float w2 = __int_as_float(e2.y), w3 = __int_as_float(e3.y);
        a0 = fmaf(w0, bf_lo(v0.x), a0); a1 = fmaf(w0, bf_hi(v0.x), a1);
        a2 = fmaf(w0, bf_lo(v0.y), a2); a3 = fmaf(w0, bf_hi(v0.y), a3);
        a0 = fmaf(w1, bf_lo(v1.x), a0); a1 = fmaf(w1, bf_hi(v1.x), a1);
        a2 = fmaf(w1, bf_lo(v1.y), a2); a3 = fmaf(w1, bf_hi(v1.y), a3);
        a0 = fmaf(w2, bf_lo(v2.x), a0); a1 = fmaf(w2, bf_hi(v2.x), a1);
        a2 = fmaf(w2, bf_lo(v2.y), a2); a3 = fmaf(w2, bf_hi(v2.y), a3);
        a0 = fmaf(w3, bf_lo(v3.x), a0); a1 = fmaf(w3, bf_hi(v3.x), a1);
        a2 = fmaf(w3, bf_lo(v3.y), a2); a3 = fmaf(w3, bf_hi(v3.y), a3);
    }
    for (; i < end; i += 2) {
        int2 e = einfo[i];
        uint2 vv = H[(size_t)e.x * 32 + l];
        float w = __int_as_float(e.y);
        a0 = fmaf(w, bf_lo(vv.x), a0); a1 = fmaf(w, bf_hi(vv.x), a1);
        a2 = fmaf(w, bf_lo(vv.y), a2); a3 = fmaf(w, bf_hi(vv.y), a3);
    }
    a0 += __shfl_xor(a0, 32);
    a1 += __shfl_xor(a1, 32);
    a2 += __shfl_xor(a2, 32);
    a3 += __shfl_xor(a3, 32);
    if (half == 0) {
        float4 bb = ((const float4*)bias)[l];
        float o0 = fmaxf(a0 + bb.x, 0.f);
        float o1 = fmaxf(a1 + bb.y, 0.f);
        float o2 = fmaxf(a2 + bb.z, 0.f);
        float o3 = fmaxf(a3 + bb.w, 0.f);
        if (OUT_BF16) {
            unsigned int p0 = (unsigned int)f2bf(o0) | ((unsigned int)f2bf(o1) << 16);
            unsigned int p1 = (unsigned int)f2bf(o2) | ((unsigned int)f2bf(o3) << 16);
            ((uint2*)out)[(size_t)v * 32 + l] = make_uint2(p0, p1);
        } else {
            ((float4*)out)[(size_t)v * 32 + l] = make_float4(o0, o1, o2, o3);
        }
    }
}

static inline size_t align_up(size_t x, size_t a) { return (x + a - 1) & ~(a - 1); }

extern "C" void kernel_launch(void* const* d_in, const int* in_sizes, int n_in,
                              void* d_out, int out_size, void* d_ws, size_t ws_size,
                              hipStream_t stream) {
    const float* x  = (const float*)d_in[0];
    const int*   ei = (const int*)d_in[1];
    const float* W1 = (const float*)d_in[2];
    const float* b1 = (const float*)d_in[3];
    const float* W2 = (const float*)d_in[4];
    const float* b2 = (const float*)d_in[5];

    const int N = in_sizes[0] / DIN;   // 100000
    const int E = in_sizes[1] / 2;     // 1600000
    const int* src = ei;
    const int* dst = ei + E;

    // workspace partition
    char* base = (char*)d_ws;
    size_t off = 0;
    int* cnt = (int*)(base + off);          off = align_up(off + (size_t)N * 4, 256);
    int* rowptr = (int*)(base + off);       off = align_up(off + (size_t)(N + 1) * 4, 256);
    int* cursor = (int*)(base + off);       off = align_up(off + (size_t)N * 4, 256);
    float* dinv = (float*)(base + off);     off = align_up(off + (size_t)N * 4, 256);
    int* bsum = (int*)(base + off);         off = align_up(off + 512 * 4, 256);
    int2* einfo = (int2*)(base + off);      off = align_up(off + (size_t)E * 8, 256);
    unsigned short* Wt1 = (unsigned short*)(base + off); off = align_up(off + (size_t)128 * 256 * 2, 256);
    unsigned short* Wt2 = (unsigned short*)(base + off); off = align_up(off + (size_t)128 * 128 * 2, 256);
    unsigned short* hb  = (unsigned short*)(base + off); off = align_up(off + (size_t)N * 128 * 2, 256);
    unsigned short* a1b = (unsigned short*)(base + off); off = align_up(off + (size_t)N * 128 * 2, 256);

    float* out = (float*)d_out;
    const int NB = (N + 255) / 256;

    hipMemsetAsync(cnt, 0, (size_t)N * sizeof(int), stream);
    count_mp<<<1024, 256, 0, stream>>>(dst, cnt, E, N);
    dinv_k<<<(N + 255) / 256, 256, 0, stream>>>(cnt, dinv, N);
    block_sum_k<<<NB, 256, 0, stream>>>(cnt, bsum, N);
    scan_bsum_k<<<1, 512, 0, stream>>>(bsum, NB);
    scan_write_k<<<NB, 256, 0, stream>>>(cnt, bsum, rowptr, cursor, N);
    wt_k<<<(256 * 128 + 255) / 256, 256, 0, stream>>>(W1, Wt1, 256);
    wt_k<<<(128 * 128 + 255) / 256, 256, 0, stream>>>(W2, Wt2, 128);

    const int GB = (N + 127) / 128;
    const int SB = 320;
    // fused layer-1 GEMM + CSR scatter (independent work, co-scheduled)
    gemm1_scatter_k<<<SB + GB, 256, 0, stream>>>(x, Wt1, hb, N, src, dst, dinv,
                                                 cursor, einfo, E, N, SB);
    agg_k<true><<<(N + 3) / 4, 256, 0, stream>>>(hb, rowptr, einfo, dinv, b1, a1b, N);
    // layer 2
    gemm_mfma<true><<<GB, 256, 0, stream>>>(a1b, Wt2, hb, N, DH);
    agg_k<false><<<(N + 3) / 4, 256, 0, stream>>>(hb, rowptr, einfo, dinv, b2, out, N);
}

// Round 5
// 498.277 us; speedup vs baseline: 1.3840x; 1.3840x over previous
//
#include <hip/hip_runtime.h>
#include <hip/hip_bf16.h>

// ---------------------------------------------------------------------------
// GCN 2-layer forward on MI355X (gfx950).
//   prep: count_k -> dinv -> prefix-scan -> rowptr
//   CSR build (2-phase, write-amp aware; R3 single-pass scatter wrote 101MB
//   HBM for 12.8MB payload; R4 multipass failed - windows shared across
//   non-coherent XCD L2s):
//     bucket_k: 512 blocks bin edges into 196 dst-buckets (512 nodes each),
//       LDS histogram + one global-atomic run-reservation per (block,bucket),
//       ~128B contiguous runs -> ~1.5x write amp on 12.8MB
//     scatter2_k: 1 block (1024 thr) per bucket; LDS cursors from rowptr;
//       random writes confined to the bucket's 64KB CSR window, all from ONE
//       CU/XCD -> merged in that XCD's L2 -> ~1x write amp
//   L1: gemm_mfma<A=f32>(x,Wt1)->h_bf16 ; agg<out=bf16> -> a1_bf16
//   L2: gemm_mfma<A=bf16>(a1,Wt2)->h_bf16 ; agg<out=f32> -> d_out
// GEMM: MFMA 16x16x32 bf16, 128 rows/block, B staged fragment-major in LDS
// (stride-1 b128, conflict-free). agg: 1 wave/node, half-wave per 256B row,
// 8 gathers in flight, fp32 accum.
// ---------------------------------------------------------------------------

#define DIN 256
#define DH 128
#define BKT_SHIFT 9
#define BKT_SZ 512

typedef __attribute__((ext_vector_type(8))) short short8;
typedef __attribute__((ext_vector_type(4))) float f32x4;

__device__ __forceinline__ unsigned short f2bf(float f) {
    union { float f; unsigned int i; } c;
    c.f = f;
    unsigned int r = c.i + 0x7FFFu + ((c.i >> 16) & 1u);  // RNE
    return (unsigned short)(r >> 16);
}
__device__ __forceinline__ float bf_lo(unsigned int u) {
    union { unsigned int i; float f; } c;
    c.i = u << 16;
    return c.f;
}
__device__ __forceinline__ float bf_hi(unsigned int u) {
    union { unsigned int i; float f; } c;
    c.i = u & 0xFFFF0000u;
    return c.f;
}

// ---------------- prep ----------------
__global__ void count_k(const int* __restrict__ dst, int* __restrict__ cnt, int e) {
    int i = blockIdx.x * 256 + threadIdx.x;
    if (i < e) atomicAdd(&cnt[dst[i]], 1);
}

__global__ void dinv_k(const int* __restrict__ cnt, float* __restrict__ dinv, int n) {
    int i = blockIdx.x * 256 + threadIdx.x;
    if (i < n) dinv[i] = 1.0f / sqrtf((float)(cnt[i] + 1));
}

__global__ void block_sum_k(const int* __restrict__ cnt, int* __restrict__ bsum, int n) {
    __shared__ int s[256];
    int t = threadIdx.x;
    int i = blockIdx.x * 256 + t;
    s[t] = (i < n) ? cnt[i] : 0;
    __syncthreads();
    for (int off = 128; off > 0; off >>= 1) {
        if (t < off) s[t] += s[t + off];
        __syncthreads();
    }
    if (t == 0) bsum[blockIdx.x] = s[0];
}

__global__ void scan_bsum_k(int* __restrict__ bsum, int nb) {
    __shared__ int s[512];
    int t = threadIdx.x;
    s[t] = (t < nb) ? bsum[t] : 0;
    __syncthreads();
    for (int off = 1; off < 512; off <<= 1) {
        int x = (t >= off) ? s[t - off] : 0;
        __syncthreads();
        s[t] += x;
        __syncthreads();
    }
    if (t < nb) bsum[t] = (t == 0) ? 0 : s[t - 1];
}

__global__ void scan_write_k(const int* __restrict__ cnt, const int* __restrict__ bsum,
                             int* __restrict__ rowptr, int n) {
    __shared__ int s[256];
    int t = threadIdx.x;
    int i = blockIdx.x * 256 + t;
    int c = (i < n) ? cnt[i] : 0;
    s[t] = c;
    __syncthreads();
    for (int off = 1; off < 256; off <<= 1) {
        int x = (t >= off) ? s[t - off] : 0;
        __syncthreads();
        s[t] += x;
        __syncthreads();
    }
    int excl = s[t] - c + bsum[blockIdx.x];
    if (i < n) {
        rowptr[i] = excl;
        if (i == n - 1) rowptr[n] = excl + c;
    }
}

// bcur[b] = rowptr[b*512] (start of bucket b's CSR region)
__global__ void init_bcur_k(const int* __restrict__ rowptr, int* __restrict__ bcur, int nbkt) {
    int b = threadIdx.x;
    if (b < nbkt) bcur[b] = rowptr[b << BKT_SHIFT];
}

// W [K][128] f32 -> Wt [128][K] bf16
__global__ void wt_k(const float* __restrict__ W, unsigned short* __restrict__ Wt, int K) {
    int i = blockIdx.x * 256 + threadIdx.x;
    if (i < K * 128) {
        int k = i >> 7, n = i & 127;
        Wt[(size_t)n * K + k] = f2bf(W[i]);
    }
}

// ---------------- CSR build, phase 1: bucket binning ----------------
// record: .x = src | (dst_low9 << 20)   (src<2^17, fits), .y = weight f32
__global__ __launch_bounds__(256) void bucket_k(const int* __restrict__ src,
                                                const int* __restrict__ dst,
                                                const float* __restrict__ dinv,
                                                int* __restrict__ bcur,
                                                int2* __restrict__ tmp, int e, int n) {
    __shared__ int hist[256];
    __shared__ int rstart[256];
    int nbkt = (n + BKT_SZ - 1) >> BKT_SHIFT;  // 196 for N=100k
    int t = threadIdx.x;
    int nb = gridDim.x;
    int chunk = (e + nb - 1) / nb;
    int beg = blockIdx.x * chunk, end = min(e, beg + chunk);

    hist[t] = 0;
    __syncthreads();
    for (int i = beg + t; i < end; i += 256) atomicAdd(&hist[dst[i] >> BKT_SHIFT], 1);
    __syncthreads();
    int h = hist[t];
    if (t < nbkt && h > 0) rstart[t] = atomicAdd(&bcur[t], h);
    __syncthreads();
    hist[t] = 0;  // reuse as local run offset
    __syncthreads();
    for (int i = beg + t; i < end; i += 256) {
        int d = dst[i];
        int b = d >> BKT_SHIFT;
        int o = atomicAdd(&hist[b], 1);
        int s = src[i];
        float w = dinv[s] * dinv[d];
        tmp[rstart[b] + o] = make_int2(s | ((d & (BKT_SZ - 1)) << 20), __float_as_int(w));
    }
}

// ---------------- CSR build, phase 2: per-bucket scatter ----------------
// one block per bucket; all writes land in the bucket's contiguous CSR
// window (~64KB) from one CU -> merged in its XCD's L2.
__global__ __launch_bounds__(1024) void scatter2_k(const int2* __restrict__ tmp,
                                                   const int* __restrict__ rowptr,
                                                   int2* __restrict__ einfo, int n) {
    __shared__ int cur[BKT_SZ];
    int b = blockIdx.x;
    int t = threadIdx.x;
    int lo = b << BKT_SHIFT;
    int hi = min(n, lo + BKT_SZ);
    int nn = hi - lo;
    if (t < nn) cur[t] = rowptr[lo + t];
    __syncthreads();
    int beg = rowptr[lo], end = rowptr[hi];
    for (int i = beg + t; i < end; i += 1024) {
        int2 r = tmp[i];
        int dlow = (r.x >> 20) & (BKT_SZ - 1);
        int pos = atomicAdd(&cur[dlow], 1);
        einfo[pos] = make_int2(r.x & 0xFFFFF, r.y);
    }
}

// ---------------- GEMM (MFMA bf16) ----------------
// C[M,128] = A[M,K] @ Wt^T ; Wt is [128][K] bf16. Output Hb [M][128] bf16.
template <bool A_BF16>
__global__ __launch_bounds__(256) void gemm_mfma(const void* __restrict__ Av,
                                                 const unsigned short* __restrict__ Wt,
                                                 unsigned short* __restrict__ Hb,
                                                 int M, int K) {
    __shared__ unsigned short Bt[16384];  // 32 KB: 32 frag-groups x 1024 B
    const int t = threadIdx.x;
    const int w = t >> 6;
    const int lane = t & 63;
    const int l15 = lane & 15;
    const int quad = lane >> 4;
    const int row0 = blockIdx.x * 128 + w * 32;

    const float* Af = (const float*)Av;
    const unsigned short* Ab = (const unsigned short*)Av;

    f32x4 acc[2][8];
#pragma unroll
    for (int rt = 0; rt < 2; ++rt)
#pragma unroll
        for (int ct = 0; ct < 8; ++ct)
#pragma unroll
            for (int j = 0; j < 4; ++j) acc[rt][ct][j] = 0.0f;

    for (int kc = 0; kc < K; kc += 128) {
        if (kc) __syncthreads();
#pragma unroll
        for (int i = 0; i < 8; ++i) {
            int fg = w * 8 + i;
            int ks = fg >> 3, ct = fg & 7;
            int nn = ct * 16 + l15;
            int gk = ks * 32 + quad * 8;
            *(short8*)&Bt[fg * 512 + lane * 8] =
                *(const short8*)(Wt + (size_t)nn * K + kc + gk);
        }
        __syncthreads();
#pragma unroll
        for (int ks = 0; ks < 4; ++ks) {
            int kk = ks * 32 + quad * 8;
            short8 af[2];
#pragma unroll
            for (int rt = 0; rt < 2; ++rt) {
                int row = row0 + rt * 16 + l15;
                if (row < M) {
                    if (A_BF16) {
                        af[rt] = *(const short8*)(Ab + (size_t)row * K + kc + kk);
                    } else {
                        const float* p = Af + (size_t)row * K + kc + kk;
                        float4 x0 = *(const float4*)p;
                        float4 x1 = *(const float4*)(p + 4);
                        af[rt][0] = (short)f2bf(x0.x);
                        af[rt][1] = (short)f2bf(x0.y);
                        af[rt][2] = (short)f2bf(x0.z);
                        af[rt][3] = (short)f2bf(x0.w);
                        af[rt][4] = (short)f2bf(x1.x);
                        af[rt][5] = (short)f2bf(x1.y);
                        af[rt][6] = (short)f2bf(x1.z);
                        af[rt][7] = (short)f2bf(x1.w);
                    }
                } else {
#pragma unroll
                    for (int j = 0; j < 8; ++j) af[rt][j] = 0;
                }
            }
#pragma unroll
            for (int ct = 0; ct < 8; ++ct) {
                short8 bfr = *(const short8*)&Bt[(ks * 8 + ct) * 512 + lane * 8];
                acc[0][ct] = __builtin_amdgcn_mfma_f32_16x16x32_bf16(af[0], bfr, acc[0][ct], 0, 0, 0);
                acc[1][ct] = __builtin_amdgcn_mfma_f32_16x16x32_bf16(af[1], bfr, acc[1][ct], 0, 0, 0);
            }
        }
    }
#pragma unroll
    for (int rt = 0; rt < 2; ++rt)
#pragma unroll
        for (int r = 0; r < 4; ++r) {
            int row = row0 + rt * 16 + quad * 4 + r;
            if (row < M) {
                unsigned short* o = Hb + (size_t)row * 128 + l15;
#pragma unroll
                for (int ct = 0; ct < 8; ++ct) o[ct * 16] = f2bf(acc[rt][ct][r]);
            }
        }
}

// ---------------- aggregation ----------------
// 1 wave/node; half-wave (32 lanes) covers a 256B bf16 row via uint2/lane.
// halves process even/odd edges; unroll 4 -> 8 edges in flight.
template <bool OUT_BF16>
__global__ __launch_bounds__(256) void agg_k(const unsigned short* __restrict__ Hb,
                                             const int* __restrict__ rowptr,
                                             const int2* __restrict__ einfo,
                                             const float* __restrict__ dinv,
                                             const float* __restrict__ bias,
                                             void* __restrict__ out, int n) {
    int v = blockIdx.x * 4 + (threadIdx.x >> 6);
    int lane = threadIdx.x & 63;
    if (v >= n) return;
    int l = lane & 31, half = lane >> 5;
    const uint2* __restrict__ H = (const uint2*)Hb;  // row = 32 x uint2
    float a0 = 0.f, a1 = 0.f, a2 = 0.f, a3 = 0.f;
    if (half == 0) {
        float dv = dinv[v];
        float self = dv * dv;
        uint2 hv = H[(size_t)v * 32 + l];
        a0 = self * bf_lo(hv.x); a1 = self * bf_hi(hv.x);
        a2 = self * bf_lo(hv.y); a3 = self * bf_hi(hv.y);
    }
    int end = rowptr[v + 1];
    int i = rowptr[v] + half;
    for (; i + 6 < end; i += 8) {
        int2 e0 = einfo[i], e1 = einfo[i + 2], e2 = einfo[i + 4], e3 = einfo[i + 6];
        uint2 v0 = H[(size_t)e0.x * 32 + l];
        uint2 v1 = H[(size_t)e1.x * 32 + l];
        uint2 v2 = H[(size_t)e2.x * 32 + l];
        uint2 v3 = H[(size_t)e3.x * 32 + l];
        float w0 = __int_as_float(e0.y), w1 = __int_as_float(e1.y);
        float w2 = __int_as_float(e2.y), w3 = __int_as_float(e3.y);
        a0 = fmaf(w0, bf_lo(v0.x), a0); a1 = fmaf(w0, bf_hi(v0.x), a1);
        a2 = fmaf(w0, bf_lo(v0.y), a2); a3 = fmaf(w0, bf_hi(v0.y), a3);
        a0 = fmaf(w1, bf_lo(v1.x), a0); a1 = fmaf(w1, bf_hi(v1.x), a1);
        a2 = fmaf(w1, bf_lo(v1.y), a2); a3 = fmaf(w1, bf_hi(v1.y), a3);
        a0 = fmaf(w2, bf_lo(v2.x), a0); a1 = fmaf(w2, bf_hi(v2.x), a1);
        a2 = fmaf(w2, bf_lo(v2.y), a2); a3 = fmaf(w2, bf_hi(v2.y), a3);
        a0 = fmaf(w3, bf_lo(v3.x), a0); a1 = fmaf(w3, bf_hi(v3.x), a1);
        a2 = fmaf(w3, bf_lo(v3.y), a2); a3 = fmaf(w3, bf_hi(v3.y), a3);
    }
    for (; i < end; i += 2) {
        int2 e = einfo[i];
        uint2 vv = H[(size_t)e.x * 32 + l];
        float w = __int_as_float(e.y);
        a0 = fmaf(w, bf_lo(vv.x), a0); a1 = fmaf(w, bf_hi(vv.x), a1);
        a2 = fmaf(w, bf_lo(vv.y), a2); a3 = fmaf(w, bf_hi(vv.y), a3);
    }
    a0 += __shfl_xor(a0, 32);
    a1 += __shfl_xor(a1, 32);
    a2 += __shfl_xor(a2, 32);
    a3 += __shfl_xor(a3, 32);
    if (half == 0) {
        float4 bb = ((const float4*)bias)[l];
        float o0 = fmaxf(a0 + bb.x, 0.f);
        float o1 = fmaxf(a1 + bb.y, 0.f);
        float o2 = fmaxf(a2 + bb.z, 0.f);
        float o3 = fmaxf(a3 + bb.w, 0.f);
        if (OUT_BF16) {
            unsigned int p0 = (unsigned int)f2bf(o0) | ((unsigned int)f2bf(o1) << 16);
            unsigned int p1 = (unsigned int)f2bf(o2) | ((unsigned int)f2bf(o3) << 16);
            ((uint2*)out)[(size_t)v * 32 + l] = make_uint2(p0, p1);
        } else {
            ((float4*)out)[(size_t)v * 32 + l] = make_float4(o0, o1, o2, o3);
        }
    }
}

static inline size_t align_up(size_t x, size_t a) { return (x + a - 1) & ~(a - 1); }

extern "C" void kernel_launch(void* const* d_in, const int* in_sizes, int n_in,
                              void* d_out, int out_size, void* d_ws, size_t ws_size,
                              hipStream_t stream) {
    const float* x  = (const float*)d_in[0];
    const int*   ei = (const int*)d_in[1];
    const float* W1 = (const float*)d_in[2];
    const float* b1 = (const float*)d_in[3];
    const float* W2 = (const float*)d_in[4];
    const float* b2 = (const float*)d_in[5];

    const int N = in_sizes[0] / DIN;   // 100000
    const int E = in_sizes[1] / 2;     // 1600000
    const int* src = ei;
    const int* dst = ei + E;
    const int NBKT = (N + BKT_SZ - 1) >> BKT_SHIFT;  // 196

    // workspace partition
    char* base = (char*)d_ws;
    size_t off = 0;
    int* cnt = (int*)(base + off);          off = align_up(off + (size_t)N * 4, 256);
    int* rowptr = (int*)(base + off);       off = align_up(off + (size_t)(N + 1) * 4, 256);
    float* dinv = (float*)(base + off);     off = align_up(off + (size_t)N * 4, 256);
    int* bsum = (int*)(base + off);         off = align_up(off + 512 * 4, 256);
    int* bcur = (int*)(base + off);         off = align_up(off + 256 * 4, 256);
    int2* tmp = (int2*)(base + off);        off = align_up(off + (size_t)E * 8, 256);
    int2* einfo = (int2*)(base + off);      off = align_up(off + (size_t)E * 8, 256);
    unsigned short* Wt1 = (unsigned short*)(base + off); off = align_up(off + (size_t)128 * 256 * 2, 256);
    unsigned short* Wt2 = (unsigned short*)(base + off); off = align_up(off + (size_t)128 * 128 * 2, 256);
    unsigned short* hb  = (unsigned short*)(base + off); off = align_up(off + (size_t)N * 128 * 2, 256);
    unsigned short* a1b = (unsigned short*)(base + off); off = align_up(off + (size_t)N * 128 * 2, 256);

    float* out = (float*)d_out;
    const int NB = (N + 255) / 256;

    hipMemsetAsync(cnt, 0, (size_t)N * sizeof(int), stream);
    count_k<<<(E + 255) / 256, 256, 0, stream>>>(dst, cnt, E);
    dinv_k<<<NB, 256, 0, stream>>>(cnt, dinv, N);
    block_sum_k<<<NB, 256, 0, stream>>>(cnt, bsum, N);
    scan_bsum_k<<<1, 512, 0, stream>>>(bsum, NB);
    scan_write_k<<<NB, 256, 0, stream>>>(cnt, bsum, rowptr, N);
    init_bcur_k<<<1, 256, 0, stream>>>(rowptr, bcur, NBKT);
    wt_k<<<(256 * 128 + 255) / 256, 256, 0, stream>>>(W1, Wt1, 256);
    wt_k<<<(128 * 128 + 255) / 256, 256, 0, stream>>>(W2, Wt2, 128);

    // CSR build: bucket binning then XCD-local scatter
    bucket_k<<<512, 256, 0, stream>>>(src, dst, dinv, bcur, tmp, E, N);
    scatter2_k<<<NBKT, 1024, 0, stream>>>(tmp, rowptr, einfo, N);

    const int GB = (N + 127) / 128;
    // layer 1
    gemm_mfma<false><<<GB, 256, 0, stream>>>(x, Wt1, hb, N, DIN);
    agg_k<true><<<(N + 3) / 4, 256, 0, stream>>>(hb, rowptr, einfo, dinv, b1, a1b, N);
    // layer 2
    gemm_mfma<true><<<GB, 256, 0, stream>>>(a1b, Wt2, hb, N, DH);
    agg_k<false><<<(N + 3) / 4, 256, 0, stream>>>(hb, rowptr, einfo, dinv, b2, out, N);
}